// Round 1
// baseline (1529.894 us; speedup 1.0000x reference)
//
#include <hip/hip_runtime.h>
#include <hip/hip_bf16.h>

// MACE layer: edge kernel (radial MLP + messages + atomic scatter) + node kernel.
// ws layout: A[N][C][4] f32 accumulators (slot 0 = a0, slots 1..3 = a1).

constexpr int kN = 50000;
constexpr int kE = 400000;
constexpr int kC = 64;

__device__ __forceinline__ float silu_f(float x) {
    // x * sigmoid(x); fast exp is fine (threshold 1.175e-1)
    float t = __expf(-x);
    return x / (1.0f + t);
}

// ---------------------------------------------------------------------------
// Edge kernel: one wave processes 4 edges per iteration.
// lane = channel/hidden index. W_r2, W_r3 staged in LDS (W_r3 transposed to
// [j][c][k] so the inner loop reads one float4 per j). Per-wave LDS buffers
// broadcast h1/h2 across lanes (wave-synchronous, no __syncthreads needed).
// ---------------------------------------------------------------------------
__global__ __launch_bounds__(1024, 4)
void edge_kernel(const float* __restrict__ ev,
                 const float* __restrict__ nf,
                 const float* __restrict__ rad,
                 const int* __restrict__ snd,
                 const int* __restrict__ rcv,
                 const float* __restrict__ W1,
                 const float* __restrict__ W2,
                 const float* __restrict__ W3,
                 float* __restrict__ A)
{
    __shared__ float W2s[4096];          // [j][t]           16 KB
    __shared__ float W3s[16384];         // [j][t][k]        64 KB
    __shared__ float h1s[16][64][4];     // [wave][j][e]     16 KB
    __shared__ float h2s[16][64][4];     // [wave][j][e]     16 KB

    const int tid = threadIdx.x;
    for (int i = tid; i < 4096; i += 1024) W2s[i] = W2[i];
    for (int i = tid; i < 16384; i += 1024) {
        int j = i >> 8, rem = i & 255;
        int k = rem >> 6, t = rem & 63;
        W3s[(((j << 6) | t) << 2) | k] = W3[i];
    }
    __syncthreads();

    const int lane = tid & 63;
    const int wvi = tid >> 6;
    const int gw = (blockIdx.x << 4) | wvi;
    const int nw = gridDim.x << 4;

    float w1c[8];
#pragma unroll
    for (int r = 0; r < 8; ++r) w1c[r] = W1[(r << 6) | lane];

    for (int base = gw * 4; base < kE; base += nw * 4) {
        // ---- h1 = silu(rad @ W1), lane t owns hidden unit t, 4 edges ----
        float h1[4];
#pragma unroll
        for (int e = 0; e < 4; ++e) {
            const float4 ra = *(const float4*)&rad[(base + e) * 8];
            const float4 rb = *(const float4*)&rad[(base + e) * 8 + 4];
            float acc = ra.x * w1c[0] + ra.y * w1c[1] + ra.z * w1c[2] + ra.w * w1c[3]
                      + rb.x * w1c[4] + rb.y * w1c[5] + rb.z * w1c[6] + rb.w * w1c[7];
            h1[e] = silu_f(acc);
        }
        *(float4*)&h1s[wvi][lane][0] = make_float4(h1[0], h1[1], h1[2], h1[3]);
        __builtin_amdgcn_wave_barrier();

        // ---- h2 = silu(h1 @ W2) ----
        float a2x = 0.f, a2y = 0.f, a2z = 0.f, a2w = 0.f;
#pragma unroll 16
        for (int j = 0; j < 64; ++j) {
            const float wj = W2s[(j << 6) | lane];
            const float4 hv = *(const float4*)&h1s[wvi][j][0];
            a2x += hv.x * wj; a2y += hv.y * wj; a2z += hv.z * wj; a2w += hv.w * wj;
        }
        __builtin_amdgcn_wave_barrier();
        *(float4*)&h2s[wvi][lane][0] =
            make_float4(silu_f(a2x), silu_f(a2y), silu_f(a2z), silu_f(a2w));
        __builtin_amdgcn_wave_barrier();

        // ---- w = h2 @ W3 : aw[e][k], k = output group ----
        float aw[4][4];
#pragma unroll
        for (int e = 0; e < 4; ++e)
#pragma unroll
            for (int k = 0; k < 4; ++k) aw[e][k] = 0.0f;
#pragma unroll 8
        for (int j = 0; j < 64; ++j) {
            const float4 w4 = *(const float4*)&W3s[(((j << 6) | lane) << 2)];
            const float4 hv = *(const float4*)&h2s[wvi][j][0];
            aw[0][0] += hv.x * w4.x; aw[0][1] += hv.x * w4.y; aw[0][2] += hv.x * w4.z; aw[0][3] += hv.x * w4.w;
            aw[1][0] += hv.y * w4.x; aw[1][1] += hv.y * w4.y; aw[1][2] += hv.y * w4.z; aw[1][3] += hv.y * w4.w;
            aw[2][0] += hv.z * w4.x; aw[2][1] += hv.z * w4.y; aw[2][2] += hv.z * w4.z; aw[2][3] += hv.z * w4.w;
            aw[3][0] += hv.w * w4.x; aw[3][1] += hv.w * w4.y; aw[3][2] += hv.w * w4.z; aw[3][3] += hv.w * w4.w;
        }

        // ---- messages + atomic scatter ----
#pragma unroll
        for (int e = 0; e < 4; ++e) {
            const int eid = base + e;
            const int sid = snd[eid];
            const int rid = rcv[eid];
            const float ex = ev[eid * 3 + 0], ey = ev[eid * 3 + 1], ez = ev[eid * 3 + 2];
            const float ri = rsqrtf(ex * ex + ey * ey + ez * ez + 1e-12f);
            const float y0 = 1.7320508075688772f * ex * ri;
            const float y1 = 1.7320508075688772f * ey * ri;
            const float y2 = 1.7320508075688772f * ez * ri;
            const float4 xv = *(const float4*)&nf[(((sid << 6) | lane) << 2)];
            const float dot1 = xv.y * y0 + xv.z * y1 + xv.w * y2;
            const float m0 = aw[e][0] * xv.x + aw[e][1] * dot1;
            const float t2 = aw[e][2] * xv.x;
            float* ap = &A[(((rid << 6) | lane) << 2)];
            unsafeAtomicAdd(ap + 0, m0);
            unsafeAtomicAdd(ap + 1, t2 * y0 + aw[e][3] * xv.y);
            unsafeAtomicAdd(ap + 2, t2 * y1 + aw[e][3] * xv.z);
            unsafeAtomicAdd(ap + 3, t2 * y2 + aw[e][3] * xv.w);
        }
    }
}

// ---------------------------------------------------------------------------
// Node kernel: one wave per node, lane = channel. Shared 64x64 weights in LDS;
// species-selected Wres0/Wres1 rows read from global (coalesced, L2-resident).
// ---------------------------------------------------------------------------
__global__ __launch_bounds__(512, 4)
void node_kernel(const float* __restrict__ nf,
                 const int* __restrict__ spc,
                 const float* __restrict__ Wl0,
                 const float* __restrict__ Wl1,
                 const float* __restrict__ Ws0,
                 const float* __restrict__ Ws1,
                 const float* __restrict__ Wp0,
                 const float* __restrict__ Wp1,
                 const float* __restrict__ Wr0,
                 const float* __restrict__ Wr1,
                 const float* __restrict__ Wrd,
                 const float* __restrict__ A,
                 float* __restrict__ out0,
                 float* __restrict__ outF)
{
    __shared__ float L0s[4096], L1s[4096], P0s[4096], P1s[4096];  // 64 KB
    __shared__ float bufA[8][64][4];   // a (then B) broadcast      8 KB
    __shared__ float bufX[8][64][4];   // x broadcast               8 KB

    const int tid = threadIdx.x;
    for (int i = tid; i < 4096; i += 512) {
        L0s[i] = Wl0[i]; L1s[i] = Wl1[i]; P0s[i] = Wp0[i]; P1s[i] = Wp1[i];
    }
    __syncthreads();

    const int lane = tid & 63;
    const int wvi = tid >> 6;
    const int n = (int)(blockIdx.x << 3) | wvi;

    float4 av = *(const float4*)&A[(((n << 6) | lane) << 2)];
    av.x *= 0.125f; av.y *= 0.125f; av.z *= 0.125f; av.w *= 0.125f;   // /AVG
    *(float4*)&bufA[wvi][lane][0] = av;
    const float4 xv = *(const float4*)&nf[(((n << 6) | lane) << 2)];
    *(float4*)&bufX[wvi][lane][0] = xv;
    __builtin_amdgcn_wave_barrier();

    // A0 = a0 @ Wl0 ; A1_i = a1_i @ Wl1   (lane = output channel d)
    float A0 = 0.f, A1x = 0.f, A1y = 0.f, A1z = 0.f;
#pragma unroll 16
    for (int c = 0; c < 64; ++c) {
        const float4 ac = *(const float4*)&bufA[wvi][c][0];
        const float l0 = L0s[(c << 6) | lane];
        const float l1 = L1s[(c << 6) | lane];
        A0 += ac.x * l0; A1x += ac.y * l1; A1y += ac.z * l1; A1z += ac.w * l1;
    }

    const int s = spc[n];
    const float n1 = A1x * A1x + A1y * A1y + A1z * A1z;
    const float* w0p = &Ws0[((s << 6) | lane) * 5];
    const float A0sq = A0 * A0;
    const float B0 = w0p[0] * A0 + w0p[1] * A0sq + w0p[2] * A0sq * A0
                   + w0p[3] * n1 + w0p[4] * A0 * n1;
    const float4 w1v = *(const float4*)&Ws1[(((s << 6) | lane) << 2)];
    const float g = w1v.x + w1v.y * A0 + w1v.z * A0sq + w1v.w * n1;

    __builtin_amdgcn_wave_barrier();
    *(float4*)&bufA[wvi][lane][0] = make_float4(B0, g * A1x, g * A1y, g * A1z);
    __builtin_amdgcn_wave_barrier();

    // F0 = B0 @ Wp0 + x0 @ Wres0[s] ; F1_i = B1_i @ Wp1 + x1_i @ Wres1[s]
    const float* wr0 = &Wr0[s << 12];
    const float* wr1 = &Wr1[s << 12];
    float F0 = 0.f, F1x = 0.f, F1y = 0.f, F1z = 0.f;
#pragma unroll 8
    for (int c = 0; c < 64; ++c) {
        const float4 bv = *(const float4*)&bufA[wvi][c][0];
        const float4 xc = *(const float4*)&bufX[wvi][c][0];
        const float p0 = P0s[(c << 6) | lane];
        const float p1 = P1s[(c << 6) | lane];
        const float r0 = wr0[(c << 6) | lane];
        const float r1 = wr1[(c << 6) | lane];
        F0  += bv.x * p0 + xc.x * r0;
        F1x += bv.y * p1 + xc.y * r1;
        F1y += bv.z * p1 + xc.z * r1;
        F1z += bv.w * p1 + xc.w * r1;
    }

    *(float4*)&outF[(((n << 6) | lane) << 2)] = make_float4(F0, F1x, F1y, F1z);

    float v = F0 * Wrd[lane];
#pragma unroll
    for (int off = 32; off > 0; off >>= 1) v += __shfl_down(v, off, 64);
    if (lane == 0) out0[n] = v;
}

extern "C" void kernel_launch(void* const* d_in, const int* in_sizes, int n_in,
                              void* d_out, int out_size, void* d_ws, size_t ws_size,
                              hipStream_t stream)
{
    const float* edge_vectors = (const float*)d_in[0];
    const float* node_feats   = (const float*)d_in[1];
    const int*   node_species = (const int*)d_in[2];
    const float* radial       = (const float*)d_in[3];
    const int*   senders      = (const int*)d_in[4];
    const int*   receivers    = (const int*)d_in[5];
    const float* W_r1   = (const float*)d_in[6];
    const float* W_r2   = (const float*)d_in[7];
    const float* W_r3   = (const float*)d_in[8];
    const float* W_lin0 = (const float*)d_in[9];
    const float* W_lin1 = (const float*)d_in[10];
    const float* Wsc0   = (const float*)d_in[11];
    const float* Wsc1   = (const float*)d_in[12];
    const float* Wp0    = (const float*)d_in[13];
    const float* Wp1    = (const float*)d_in[14];
    const float* Wres0  = (const float*)d_in[15];
    const float* Wres1  = (const float*)d_in[16];
    const float* W_read = (const float*)d_in[17];

    float* A = (float*)d_ws;                         // N*C*4 f32 = 51.2 MB
    hipMemsetAsync(A, 0, (size_t)kN * kC * 4 * sizeof(float), stream);

    edge_kernel<<<256, 1024, 0, stream>>>(edge_vectors, node_feats, radial,
                                          senders, receivers, W_r1, W_r2, W_r3, A);

    float* out0 = (float*)d_out;
    float* outF = out0 + kN;
    node_kernel<<<kN / 8, 512, 0, stream>>>(node_feats, node_species,
                                            W_lin0, W_lin1, Wsc0, Wsc1,
                                            Wp0, Wp1, Wres0, Wres1, W_read,
                                            A, out0, outF);
}

// Round 2
// 831.525 us; speedup vs baseline: 1.8399x; 1.8399x over previous
//
#include <hip/hip_runtime.h>
#include <hip/hip_bf16.h>

// MACE layer, sorted-scatter version:
//   k1 histogram(receivers) -> cnt
//   k2 single-wave chunked exclusive scan -> off, cur
//   k3 scatter edge ids by receiver -> eidx
//   k4 edge kernel: radial MLP + messages, streaming bf16 store m[e][C][4]
//   k5 fused gather(+/AVG) + node phase -> outputs
// Fallback (ws too small): round-1 atomic path.

constexpr int kN = 50000;
constexpr int kE = 400000;
constexpr int kC = 64;

// ws layout (new path)
constexpr size_t kOffM    = 0;                          // kE*256 bf16 = 204,800,000 B
constexpr size_t kOffCnt  = 204800000;                  // kN ints
constexpr size_t kOffOff  = 205000000;                  // (kN+1) ints
constexpr size_t kOffCur  = 205200016;                  // kN ints
constexpr size_t kOffEidx = 205400016;                  // kE ints
constexpr size_t kWsNeed  = 207000032;

__device__ __forceinline__ float silu_f(float x) {
    float t = __expf(-x);
    return x / (1.0f + t);
}

__device__ __forceinline__ unsigned short f2bf(float f) {
    unsigned u = __float_as_uint(f);
    unsigned r = (u + 0x7FFFu + ((u >> 16) & 1u)) >> 16;
    return (unsigned short)r;
}
__device__ __forceinline__ float bf2f(unsigned short b) {
    return __uint_as_float(((unsigned)b) << 16);
}

// ---------------------------------------------------------------------------
__global__ __launch_bounds__(256) void hist_kernel(const int* __restrict__ rcv,
                                                   int* __restrict__ cnt)
{
    int i = blockIdx.x * blockDim.x + threadIdx.x;
    int stride = gridDim.x * blockDim.x;
    for (; i < kE; i += stride) atomicAdd(&cnt[rcv[i]], 1);
}

// Single wave: lane owns a contiguous chunk; exclusive scan across lanes.
__global__ __launch_bounds__(64) void scan_kernel(const int* __restrict__ cnt,
                                                  int* __restrict__ off,
                                                  int* __restrict__ cur)
{
    const int lane = threadIdx.x;
    const int CH = (kN + 63) / 64;          // 782
    const int b = lane * CH;
    int s = 0;
    for (int i = 0; i < CH; ++i) {
        int idx = b + i;
        if (idx < kN) s += cnt[idx];
    }
    int incl = s;
    for (int d = 1; d < 64; d <<= 1) {
        int t = __shfl_up(incl, d, 64);
        if (lane >= d) incl += t;
    }
    int run = incl - s;                     // exclusive prefix
    for (int i = 0; i < CH; ++i) {
        int idx = b + i;
        if (idx < kN) {
            int c = cnt[idx];
            off[idx] = run;
            cur[idx] = run;
            run += c;
        }
    }
    if (lane == 63) off[kN] = run;
}

__global__ __launch_bounds__(256) void scatter_kernel(const int* __restrict__ rcv,
                                                      int* __restrict__ cur,
                                                      int* __restrict__ eidx)
{
    int i = blockIdx.x * blockDim.x + threadIdx.x;
    int stride = gridDim.x * blockDim.x;
    for (; i < kE; i += stride) {
        int pos = atomicAdd(&cur[rcv[i]], 1);
        eidx[pos] = i;
    }
}

// ---------------------------------------------------------------------------
// Edge kernel: one wave processes 4 edges/iter; lane = channel/hidden index.
// Output: streaming bf16 message store m[e][C][4] (512 B per edge).
// ---------------------------------------------------------------------------
__global__ __launch_bounds__(1024, 4)
void edge_kernel(const float* __restrict__ ev,
                 const float* __restrict__ nf,
                 const float* __restrict__ rad,
                 const int* __restrict__ snd,
                 const float* __restrict__ W1,
                 const float* __restrict__ W2,
                 const float* __restrict__ W3,
                 unsigned short* __restrict__ m)
{
    __shared__ float W2s[4096];          // [j][t]           16 KB
    __shared__ float W3s[16384];         // [j][t][k]        64 KB
    __shared__ float h1s[16][64][4];     // [wave][j][e]     16 KB
    __shared__ float h2s[16][64][4];     // [wave][j][e]     16 KB

    const int tid = threadIdx.x;
    for (int i = tid; i < 4096; i += 1024) W2s[i] = W2[i];
    for (int i = tid; i < 16384; i += 1024) {
        int j = i >> 8, rem = i & 255;
        int k = rem >> 6, t = rem & 63;
        W3s[(((j << 6) | t) << 2) | k] = W3[i];
    }
    __syncthreads();

    const int lane = tid & 63;
    const int wvi = tid >> 6;
    const int gw = (blockIdx.x << 4) | wvi;
    const int nw = gridDim.x << 4;

    float w1c[8];
#pragma unroll
    for (int r = 0; r < 8; ++r) w1c[r] = W1[(r << 6) | lane];

    for (int base = gw * 4; base < kE; base += nw * 4) {
        float h1[4];
#pragma unroll
        for (int e = 0; e < 4; ++e) {
            const float4 ra = *(const float4*)&rad[(base + e) * 8];
            const float4 rb = *(const float4*)&rad[(base + e) * 8 + 4];
            float acc = ra.x * w1c[0] + ra.y * w1c[1] + ra.z * w1c[2] + ra.w * w1c[3]
                      + rb.x * w1c[4] + rb.y * w1c[5] + rb.z * w1c[6] + rb.w * w1c[7];
            h1[e] = silu_f(acc);
        }
        *(float4*)&h1s[wvi][lane][0] = make_float4(h1[0], h1[1], h1[2], h1[3]);
        __builtin_amdgcn_wave_barrier();

        float a2x = 0.f, a2y = 0.f, a2z = 0.f, a2w = 0.f;
#pragma unroll 16
        for (int j = 0; j < 64; ++j) {
            const float wj = W2s[(j << 6) | lane];
            const float4 hv = *(const float4*)&h1s[wvi][j][0];
            a2x += hv.x * wj; a2y += hv.y * wj; a2z += hv.z * wj; a2w += hv.w * wj;
        }
        __builtin_amdgcn_wave_barrier();
        *(float4*)&h2s[wvi][lane][0] =
            make_float4(silu_f(a2x), silu_f(a2y), silu_f(a2z), silu_f(a2w));
        __builtin_amdgcn_wave_barrier();

        float aw[4][4];
#pragma unroll
        for (int e = 0; e < 4; ++e)
#pragma unroll
            for (int k = 0; k < 4; ++k) aw[e][k] = 0.0f;
#pragma unroll 8
        for (int j = 0; j < 64; ++j) {
            const float4 w4 = *(const float4*)&W3s[(((j << 6) | lane) << 2)];
            const float4 hv = *(const float4*)&h2s[wvi][j][0];
            aw[0][0] += hv.x * w4.x; aw[0][1] += hv.x * w4.y; aw[0][2] += hv.x * w4.z; aw[0][3] += hv.x * w4.w;
            aw[1][0] += hv.y * w4.x; aw[1][1] += hv.y * w4.y; aw[1][2] += hv.y * w4.z; aw[1][3] += hv.y * w4.w;
            aw[2][0] += hv.z * w4.x; aw[2][1] += hv.z * w4.y; aw[2][2] += hv.z * w4.z; aw[2][3] += hv.z * w4.w;
            aw[3][0] += hv.w * w4.x; aw[3][1] += hv.w * w4.y; aw[3][2] += hv.w * w4.z; aw[3][3] += hv.w * w4.w;
        }

#pragma unroll
        for (int e = 0; e < 4; ++e) {
            const int eid = base + e;
            const int sid = snd[eid];
            const float ex = ev[eid * 3 + 0], ey = ev[eid * 3 + 1], ez = ev[eid * 3 + 2];
            const float ri = rsqrtf(ex * ex + ey * ey + ez * ez + 1e-12f);
            const float y0 = 1.7320508075688772f * ex * ri;
            const float y1 = 1.7320508075688772f * ey * ri;
            const float y2 = 1.7320508075688772f * ez * ri;
            const float4 xv = *(const float4*)&nf[(((sid << 6) | lane) << 2)];
            const float dot1 = xv.y * y0 + xv.z * y1 + xv.w * y2;
            const float m0 = aw[e][0] * xv.x + aw[e][1] * dot1;
            const float t2 = aw[e][2] * xv.x;
            ushort4 q;
            q.x = f2bf(m0);
            q.y = f2bf(t2 * y0 + aw[e][3] * xv.y);
            q.z = f2bf(t2 * y1 + aw[e][3] * xv.z);
            q.w = f2bf(t2 * y2 + aw[e][3] * xv.w);
            *(ushort4*)&m[(size_t)(((eid << 6) | lane)) * 4] = q;
        }
    }
}

// ---------------------------------------------------------------------------
// Fused gather + node kernel: wave per node, lane = channel.
// ---------------------------------------------------------------------------
__global__ __launch_bounds__(512, 2)
void gnode_kernel(const float* __restrict__ nf,
                  const int* __restrict__ spc,
                  const float* __restrict__ Wl0,
                  const float* __restrict__ Wl1,
                  const float* __restrict__ Ws0,
                  const float* __restrict__ Ws1,
                  const float* __restrict__ Wp0,
                  const float* __restrict__ Wp1,
                  const float* __restrict__ Wr0,
                  const float* __restrict__ Wr1,
                  const float* __restrict__ Wrd,
                  const unsigned short* __restrict__ m,
                  const int* __restrict__ off,
                  const int* __restrict__ eidx,
                  float* __restrict__ out0,
                  float* __restrict__ outF)
{
    __shared__ float L0s[4096], L1s[4096], P0s[4096], P1s[4096];  // 64 KB
    __shared__ float bufA[8][64][4];   // 8 KB
    __shared__ float bufX[8][64][4];   // 8 KB

    const int tid = threadIdx.x;
    for (int i = tid; i < 4096; i += 512) {
        L0s[i] = Wl0[i]; L1s[i] = Wl1[i]; P0s[i] = Wp0[i]; P1s[i] = Wp1[i];
    }
    __syncthreads();

    const int lane = tid & 63;
    const int wvi = tid >> 6;
    const int n = (int)(blockIdx.x << 3) | wvi;

    // ---- gather: sum bf16 message rows of this node's edges ----
    const int beg = off[n], end = off[n + 1];
    float4 av = make_float4(0.f, 0.f, 0.f, 0.f);
    for (int i = beg; i < end; ++i) {
        const int e = eidx[i];
        const ushort4 q = *(const ushort4*)&m[(size_t)(((e << 6) | lane)) * 4];
        av.x += bf2f(q.x); av.y += bf2f(q.y); av.z += bf2f(q.z); av.w += bf2f(q.w);
    }
    av.x *= 0.125f; av.y *= 0.125f; av.z *= 0.125f; av.w *= 0.125f;   // /AVG

    *(float4*)&bufA[wvi][lane][0] = av;
    const float4 xv = *(const float4*)&nf[(((n << 6) | lane) << 2)];
    *(float4*)&bufX[wvi][lane][0] = xv;
    __builtin_amdgcn_wave_barrier();

    float A0 = 0.f, A1x = 0.f, A1y = 0.f, A1z = 0.f;
#pragma unroll 16
    for (int c = 0; c < 64; ++c) {
        const float4 ac = *(const float4*)&bufA[wvi][c][0];
        const float l0 = L0s[(c << 6) | lane];
        const float l1 = L1s[(c << 6) | lane];
        A0 += ac.x * l0; A1x += ac.y * l1; A1y += ac.z * l1; A1z += ac.w * l1;
    }

    const int s = spc[n];
    const float n1 = A1x * A1x + A1y * A1y + A1z * A1z;
    const float* w0p = &Ws0[((s << 6) | lane) * 5];
    const float A0sq = A0 * A0;
    const float B0 = w0p[0] * A0 + w0p[1] * A0sq + w0p[2] * A0sq * A0
                   + w0p[3] * n1 + w0p[4] * A0 * n1;
    const float4 w1v = *(const float4*)&Ws1[(((s << 6) | lane) << 2)];
    const float g = w1v.x + w1v.y * A0 + w1v.z * A0sq + w1v.w * n1;

    __builtin_amdgcn_wave_barrier();
    *(float4*)&bufA[wvi][lane][0] = make_float4(B0, g * A1x, g * A1y, g * A1z);
    __builtin_amdgcn_wave_barrier();

    const float* wr0 = &Wr0[s << 12];
    const float* wr1 = &Wr1[s << 12];
    float F0 = 0.f, F1x = 0.f, F1y = 0.f, F1z = 0.f;
#pragma unroll 8
    for (int c = 0; c < 64; ++c) {
        const float4 bv = *(const float4*)&bufA[wvi][c][0];
        const float4 xc = *(const float4*)&bufX[wvi][c][0];
        const float p0 = P0s[(c << 6) | lane];
        const float p1 = P1s[(c << 6) | lane];
        const float r0 = wr0[(c << 6) | lane];
        const float r1 = wr1[(c << 6) | lane];
        F0  += bv.x * p0 + xc.x * r0;
        F1x += bv.y * p1 + xc.y * r1;
        F1y += bv.z * p1 + xc.z * r1;
        F1z += bv.w * p1 + xc.w * r1;
    }

    *(float4*)&outF[(((n << 6) | lane) << 2)] = make_float4(F0, F1x, F1y, F1z);

    float v = F0 * Wrd[lane];
#pragma unroll
    for (int o = 32; o > 0; o >>= 1) v += __shfl_down(v, o, 64);
    if (lane == 0) out0[n] = v;
}

// ===========================================================================
// Fallback path (round-1): atomic scatter into A, separate node kernel.
// ===========================================================================
__global__ __launch_bounds__(1024, 4)
void edge_kernel_atomic(const float* __restrict__ ev,
                        const float* __restrict__ nf,
                        const float* __restrict__ rad,
                        const int* __restrict__ snd,
                        const int* __restrict__ rcv,
                        const float* __restrict__ W1,
                        const float* __restrict__ W2,
                        const float* __restrict__ W3,
                        float* __restrict__ A)
{
    __shared__ float W2s[4096];
    __shared__ float W3s[16384];
    __shared__ float h1s[16][64][4];
    __shared__ float h2s[16][64][4];

    const int tid = threadIdx.x;
    for (int i = tid; i < 4096; i += 1024) W2s[i] = W2[i];
    for (int i = tid; i < 16384; i += 1024) {
        int j = i >> 8, rem = i & 255;
        int k = rem >> 6, t = rem & 63;
        W3s[(((j << 6) | t) << 2) | k] = W3[i];
    }
    __syncthreads();

    const int lane = tid & 63;
    const int wvi = tid >> 6;
    const int gw = (blockIdx.x << 4) | wvi;
    const int nw = gridDim.x << 4;

    float w1c[8];
#pragma unroll
    for (int r = 0; r < 8; ++r) w1c[r] = W1[(r << 6) | lane];

    for (int base = gw * 4; base < kE; base += nw * 4) {
        float h1[4];
#pragma unroll
        for (int e = 0; e < 4; ++e) {
            const float4 ra = *(const float4*)&rad[(base + e) * 8];
            const float4 rb = *(const float4*)&rad[(base + e) * 8 + 4];
            float acc = ra.x * w1c[0] + ra.y * w1c[1] + ra.z * w1c[2] + ra.w * w1c[3]
                      + rb.x * w1c[4] + rb.y * w1c[5] + rb.z * w1c[6] + rb.w * w1c[7];
            h1[e] = silu_f(acc);
        }
        *(float4*)&h1s[wvi][lane][0] = make_float4(h1[0], h1[1], h1[2], h1[3]);
        __builtin_amdgcn_wave_barrier();

        float a2x = 0.f, a2y = 0.f, a2z = 0.f, a2w = 0.f;
#pragma unroll 16
        for (int j = 0; j < 64; ++j) {
            const float wj = W2s[(j << 6) | lane];
            const float4 hv = *(const float4*)&h1s[wvi][j][0];
            a2x += hv.x * wj; a2y += hv.y * wj; a2z += hv.z * wj; a2w += hv.w * wj;
        }
        __builtin_amdgcn_wave_barrier();
        *(float4*)&h2s[wvi][lane][0] =
            make_float4(silu_f(a2x), silu_f(a2y), silu_f(a2z), silu_f(a2w));
        __builtin_amdgcn_wave_barrier();

        float aw[4][4];
#pragma unroll
        for (int e = 0; e < 4; ++e)
#pragma unroll
            for (int k = 0; k < 4; ++k) aw[e][k] = 0.0f;
#pragma unroll 8
        for (int j = 0; j < 64; ++j) {
            const float4 w4 = *(const float4*)&W3s[(((j << 6) | lane) << 2)];
            const float4 hv = *(const float4*)&h2s[wvi][j][0];
            aw[0][0] += hv.x * w4.x; aw[0][1] += hv.x * w4.y; aw[0][2] += hv.x * w4.z; aw[0][3] += hv.x * w4.w;
            aw[1][0] += hv.y * w4.x; aw[1][1] += hv.y * w4.y; aw[1][2] += hv.y * w4.z; aw[1][3] += hv.y * w4.w;
            aw[2][0] += hv.z * w4.x; aw[2][1] += hv.z * w4.y; aw[2][2] += hv.z * w4.z; aw[2][3] += hv.z * w4.w;
            aw[3][0] += hv.w * w4.x; aw[3][1] += hv.w * w4.y; aw[3][2] += hv.w * w4.z; aw[3][3] += hv.w * w4.w;
        }

#pragma unroll
        for (int e = 0; e < 4; ++e) {
            const int eid = base + e;
            const int sid = snd[eid];
            const int rid = rcv[eid];
            const float ex = ev[eid * 3 + 0], ey = ev[eid * 3 + 1], ez = ev[eid * 3 + 2];
            const float ri = rsqrtf(ex * ex + ey * ey + ez * ez + 1e-12f);
            const float y0 = 1.7320508075688772f * ex * ri;
            const float y1 = 1.7320508075688772f * ey * ri;
            const float y2 = 1.7320508075688772f * ez * ri;
            const float4 xv = *(const float4*)&nf[(((sid << 6) | lane) << 2)];
            const float dot1 = xv.y * y0 + xv.z * y1 + xv.w * y2;
            const float m0 = aw[e][0] * xv.x + aw[e][1] * dot1;
            const float t2 = aw[e][2] * xv.x;
            float* ap = &A[(((rid << 6) | lane) << 2)];
            unsafeAtomicAdd(ap + 0, m0);
            unsafeAtomicAdd(ap + 1, t2 * y0 + aw[e][3] * xv.y);
            unsafeAtomicAdd(ap + 2, t2 * y1 + aw[e][3] * xv.z);
            unsafeAtomicAdd(ap + 3, t2 * y2 + aw[e][3] * xv.w);
        }
    }
}

__global__ __launch_bounds__(512, 2)
void node_kernel(const float* __restrict__ nf,
                 const int* __restrict__ spc,
                 const float* __restrict__ Wl0,
                 const float* __restrict__ Wl1,
                 const float* __restrict__ Ws0,
                 const float* __restrict__ Ws1,
                 const float* __restrict__ Wp0,
                 const float* __restrict__ Wp1,
                 const float* __restrict__ Wr0,
                 const float* __restrict__ Wr1,
                 const float* __restrict__ Wrd,
                 const float* __restrict__ A,
                 float* __restrict__ out0,
                 float* __restrict__ outF)
{
    __shared__ float L0s[4096], L1s[4096], P0s[4096], P1s[4096];
    __shared__ float bufA[8][64][4];
    __shared__ float bufX[8][64][4];

    const int tid = threadIdx.x;
    for (int i = tid; i < 4096; i += 512) {
        L0s[i] = Wl0[i]; L1s[i] = Wl1[i]; P0s[i] = Wp0[i]; P1s[i] = Wp1[i];
    }
    __syncthreads();

    const int lane = tid & 63;
    const int wvi = tid >> 6;
    const int n = (int)(blockIdx.x << 3) | wvi;

    float4 av = *(const float4*)&A[(((n << 6) | lane) << 2)];
    av.x *= 0.125f; av.y *= 0.125f; av.z *= 0.125f; av.w *= 0.125f;
    *(float4*)&bufA[wvi][lane][0] = av;
    const float4 xv = *(const float4*)&nf[(((n << 6) | lane) << 2)];
    *(float4*)&bufX[wvi][lane][0] = xv;
    __builtin_amdgcn_wave_barrier();

    float A0 = 0.f, A1x = 0.f, A1y = 0.f, A1z = 0.f;
#pragma unroll 16
    for (int c = 0; c < 64; ++c) {
        const float4 ac = *(const float4*)&bufA[wvi][c][0];
        const float l0 = L0s[(c << 6) | lane];
        const float l1 = L1s[(c << 6) | lane];
        A0 += ac.x * l0; A1x += ac.y * l1; A1y += ac.z * l1; A1z += ac.w * l1;
    }

    const int s = spc[n];
    const float n1 = A1x * A1x + A1y * A1y + A1z * A1z;
    const float* w0p = &Ws0[((s << 6) | lane) * 5];
    const float A0sq = A0 * A0;
    const float B0 = w0p[0] * A0 + w0p[1] * A0sq + w0p[2] * A0sq * A0
                   + w0p[3] * n1 + w0p[4] * A0 * n1;
    const float4 w1v = *(const float4*)&Ws1[(((s << 6) | lane) << 2)];
    const float g = w1v.x + w1v.y * A0 + w1v.z * A0sq + w1v.w * n1;

    __builtin_amdgcn_wave_barrier();
    *(float4*)&bufA[wvi][lane][0] = make_float4(B0, g * A1x, g * A1y, g * A1z);
    __builtin_amdgcn_wave_barrier();

    const float* wr0 = &Wr0[s << 12];
    const float* wr1 = &Wr1[s << 12];
    float F0 = 0.f, F1x = 0.f, F1y = 0.f, F1z = 0.f;
#pragma unroll 8
    for (int c = 0; c < 64; ++c) {
        const float4 bv = *(const float4*)&bufA[wvi][c][0];
        const float4 xc = *(const float4*)&bufX[wvi][c][0];
        const float p0 = P0s[(c << 6) | lane];
        const float p1 = P1s[(c << 6) | lane];
        const float r0 = wr0[(c << 6) | lane];
        const float r1 = wr1[(c << 6) | lane];
        F0  += bv.x * p0 + xc.x * r0;
        F1x += bv.y * p1 + xc.y * r1;
        F1y += bv.z * p1 + xc.z * r1;
        F1z += bv.w * p1 + xc.w * r1;
    }

    *(float4*)&outF[(((n << 6) | lane) << 2)] = make_float4(F0, F1x, F1y, F1z);

    float v = F0 * Wrd[lane];
#pragma unroll
    for (int o = 32; o > 0; o >>= 1) v += __shfl_down(v, o, 64);
    if (lane == 0) out0[n] = v;
}

// ===========================================================================
extern "C" void kernel_launch(void* const* d_in, const int* in_sizes, int n_in,
                              void* d_out, int out_size, void* d_ws, size_t ws_size,
                              hipStream_t stream)
{
    const float* edge_vectors = (const float*)d_in[0];
    const float* node_feats   = (const float*)d_in[1];
    const int*   node_species = (const int*)d_in[2];
    const float* radial       = (const float*)d_in[3];
    const int*   senders      = (const int*)d_in[4];
    const int*   receivers    = (const int*)d_in[5];
    const float* W_r1   = (const float*)d_in[6];
    const float* W_r2   = (const float*)d_in[7];
    const float* W_r3   = (const float*)d_in[8];
    const float* W_lin0 = (const float*)d_in[9];
    const float* W_lin1 = (const float*)d_in[10];
    const float* Wsc0   = (const float*)d_in[11];
    const float* Wsc1   = (const float*)d_in[12];
    const float* Wp0    = (const float*)d_in[13];
    const float* Wp1    = (const float*)d_in[14];
    const float* Wres0  = (const float*)d_in[15];
    const float* Wres1  = (const float*)d_in[16];
    const float* W_read = (const float*)d_in[17];

    float* out0 = (float*)d_out;
    float* outF = out0 + kN;

    char* ws = (char*)d_ws;

    if (ws_size >= kWsNeed) {
        unsigned short* m = (unsigned short*)(ws + kOffM);
        int* cnt  = (int*)(ws + kOffCnt);
        int* off  = (int*)(ws + kOffOff);
        int* cur  = (int*)(ws + kOffCur);
        int* eidx = (int*)(ws + kOffEidx);

        hipMemsetAsync(cnt, 0, kN * sizeof(int), stream);
        hist_kernel<<<1024, 256, 0, stream>>>(receivers, cnt);
        scan_kernel<<<1, 64, 0, stream>>>(cnt, off, cur);
        scatter_kernel<<<1024, 256, 0, stream>>>(receivers, cur, eidx);

        edge_kernel<<<256, 1024, 0, stream>>>(edge_vectors, node_feats, radial,
                                              senders, W_r1, W_r2, W_r3, m);

        gnode_kernel<<<kN / 8, 512, 0, stream>>>(node_feats, node_species,
                                                 W_lin0, W_lin1, Wsc0, Wsc1,
                                                 Wp0, Wp1, Wres0, Wres1, W_read,
                                                 m, off, eidx, out0, outF);
    } else {
        float* A = (float*)d_ws;   // N*C*4 f32 = 51.2 MB
        hipMemsetAsync(A, 0, (size_t)kN * kC * 4 * sizeof(float), stream);
        edge_kernel_atomic<<<256, 1024, 0, stream>>>(edge_vectors, node_feats, radial,
                                                     senders, receivers,
                                                     W_r1, W_r2, W_r3, A);
        node_kernel<<<kN / 8, 512, 0, stream>>>(node_feats, node_species,
                                                W_lin0, W_lin1, Wsc0, Wsc1,
                                                Wp0, Wp1, Wres0, Wres1, W_read,
                                                A, out0, outF);
    }
}

// Round 3
// 501.553 us; speedup vs baseline: 3.0503x; 1.6579x over previous
//
#include <hip/hip_runtime.h>

// MACE layer v3: counting-sort by receiver + MFMA edge MLP + streaming gather.
//   k1 hist(receivers) -> cnt
//   k2 block-parallel exclusive scan -> off, cur
//   k3 rank: pos[e] = slot within receiver segment
//   k4 edge_mfma: radial MLP (bf16 MFMA) + messages, store m at sorted pos
//   k5 gnode: contiguous segment-sum gather + node phase

typedef __attribute__((ext_vector_type(8))) short bf16x8;
typedef __attribute__((ext_vector_type(4))) float f32x4;

constexpr int kN = 50000;
constexpr int kE = 400000;

// ws layout (bytes)
constexpr size_t kOffM   = 0;            // kE*256 ushort = 204,800,000
constexpr size_t kOffCnt = 204800000;    // kN int
constexpr size_t kOffOff = 205000000;    // kN+1 int
constexpr size_t kOffCur = 205200016;    // kN int
constexpr size_t kOffPos = 205400016;    // kE int

__device__ __forceinline__ float silu_f(float x) {
    float t = __expf(-x);
    return x / (1.0f + t);
}
__device__ __forceinline__ unsigned short f2bf(float f) {
    unsigned u = __float_as_uint(f);
    unsigned r = (u + 0x7FFFu + ((u >> 16) & 1u)) >> 16;
    return (unsigned short)r;
}
__device__ __forceinline__ float bf2f(unsigned short b) {
    return __uint_as_float(((unsigned)b) << 16);
}
// byte offset into a 128B-row LDS tile with XOR-16B swizzle (bank-conflict-free
// for wave b128 frag reads: lanes 0-15 hit 8 distinct 16B slots, 2x = free)
__device__ __forceinline__ int swz128(int row, int byteoff) {
    return row * 128 + (byteoff ^ ((row & 7) << 4));
}

// ---------------------------------------------------------------------------
__global__ __launch_bounds__(256) void hist_kernel(const int* __restrict__ rcv,
                                                   int* __restrict__ cnt)
{
    int i = blockIdx.x * blockDim.x + threadIdx.x;
    int stride = gridDim.x * blockDim.x;
    for (; i < kE; i += stride) atomicAdd(&cnt[rcv[i]], 1);
}

// 1024-thread single-block exclusive scan over cnt[kN].
__global__ __launch_bounds__(1024) void scan_kernel(const int* __restrict__ cnt,
                                                    int* __restrict__ off,
                                                    int* __restrict__ cur)
{
    __shared__ int wred[16];
    const int tid = threadIdx.x;
    const int lane = tid & 63;
    const int wv = tid >> 6;
    const int CH = 49;                       // 49*1024 = 50176 >= kN
    const int b = tid * CH;
    int s = 0;
    for (int i = 0; i < CH; ++i) {
        int idx = b + i;
        if (idx < kN) s += cnt[idx];
    }
    int incl = s;
    for (int d = 1; d < 64; d <<= 1) {
        int t = __shfl_up(incl, d, 64);
        if (lane >= d) incl += t;
    }
    if (lane == 63) wred[wv] = incl;
    __syncthreads();
    if (tid < 16) {
        int o = wred[tid];
        int v = o;
        for (int d = 1; d < 16; d <<= 1) {
            int t = __shfl_up(v, d, 64);
            if (tid >= d) v += t;
        }
        wred[tid] = v - o;                   // exclusive wave base
    }
    __syncthreads();
    int run = wred[wv] + (incl - s);
    for (int i = 0; i < CH; ++i) {
        int idx = b + i;
        if (idx < kN) {
            int c = cnt[idx];
            off[idx] = run;
            cur[idx] = run;
            run += c;
        }
    }
    if (tid == 0) off[kN] = kE;
}

__global__ __launch_bounds__(256) void rank_kernel(const int* __restrict__ rcv,
                                                   int* __restrict__ cur,
                                                   int* __restrict__ pos)
{
    int i = blockIdx.x * blockDim.x + threadIdx.x;
    int stride = gridDim.x * blockDim.x;
    for (; i < kE; i += stride) pos[i] = atomicAdd(&cur[rcv[i]], 1);
}

// ---------------------------------------------------------------------------
// Edge kernel, MFMA version. Block = 512 thr (8 waves); tile = 128 edges,
// wave owns 16 edges end-to-end (no cross-wave sync in the loop).
//   h1[e][64] = silu(rad@W1)        fp32 VALU -> bf16 LDS (per-wave slab)
//   h2[e][64] = silu(h1@W2)         mfma 16x16x32: A=h1 frags, B=W2T rows
//   wT[n][e]  = sum_k W3T[n][k]h2[e][k]   mfma: A=W3T rows, B=h2 rows
//   messages: lane=channel reads wT slab, gathers nf[sender], stores bf16x4
//             at sorted position pos[e].
// ---------------------------------------------------------------------------
__global__ __launch_bounds__(512, 1)
void edge_mfma(const float* __restrict__ ev,
               const float* __restrict__ nf,
               const float* __restrict__ rad,
               const int* __restrict__ snd,
               const int* __restrict__ pos,
               const float* __restrict__ W1,
               const float* __restrict__ W2,
               const float* __restrict__ W3,
               unsigned short* __restrict__ mq)
{
    __shared__ unsigned short W2T[64 * 64];       // swz [n][k]   8 KB
    __shared__ unsigned short W3T[256 * 64];      // swz [n][k]  32 KB
    __shared__ unsigned short h1s[8][16 * 64];    // swz [e][k]  16 KB
    __shared__ unsigned short h2s[8][16 * 64];    // swz [e][k]  16 KB
    __shared__ unsigned short wTs[8][256 * 20];   // [n][e] pad-40B rows, 80 KB

    const int tid = threadIdx.x;

    // stage transposed bf16 weights (once per block)
    for (int i = tid; i < 64 * 64; i += 512) {
        int k = i >> 6, n = i & 63;
        W2T[swz128(n, 2 * k) >> 1] = f2bf(W2[i]);
    }
    for (int i = tid; i < 256 * 64; i += 512) {
        int k = i >> 8, n = i & 255;
        W3T[swz128(n, 2 * k) >> 1] = f2bf(W3[i]);
    }
    __syncthreads();

    const int lane = tid & 63;
    const int wvi = tid >> 6;
    const int l15 = lane & 15;
    const int g = lane >> 4;

    float w1r[8];
#pragma unroll
    for (int r = 0; r < 8; ++r) w1r[r] = W1[(r << 6) | lane];

    unsigned short* h1w = h1s[wvi];
    unsigned short* h2w = h2s[wvi];
    unsigned short* wTw = wTs[wvi];

    for (int t = blockIdx.x; t < kE / 128; t += gridDim.x) {
        const int et = t * 128 + wvi * 16;       // this wave's 16 edges

        // ---- h1: lane = hidden k, loop edges ----
        for (int e = 0; e < 16; ++e) {
            const float4 ra = *(const float4*)&rad[(size_t)(et + e) * 8];
            const float4 rb = *(const float4*)&rad[(size_t)(et + e) * 8 + 4];
            float acc = ra.x * w1r[0] + ra.y * w1r[1] + ra.z * w1r[2] + ra.w * w1r[3]
                      + rb.x * w1r[4] + rb.y * w1r[5] + rb.z * w1r[6] + rb.w * w1r[7];
            h1w[swz128(e, 2 * lane) >> 1] = f2bf(silu_f(acc));
        }
        __builtin_amdgcn_wave_barrier();

        // ---- A-frags of h1 (lane: row=l15, k=g*8+j, kt in {0,1}) ----
        bf16x8 a0 = *(const bf16x8*)&h1w[swz128(l15, g * 16) >> 1];
        bf16x8 a1 = *(const bf16x8*)&h1w[swz128(l15, 64 + g * 16) >> 1];

        // ---- h2 GEMM: 4 N-tiles ----
#pragma unroll
        for (int n0 = 0; n0 < 64; n0 += 16) {
            const int n = n0 + l15;
            bf16x8 b0 = *(const bf16x8*)&W2T[swz128(n, g * 16) >> 1];
            bf16x8 b1 = *(const bf16x8*)&W2T[swz128(n, 64 + g * 16) >> 1];
            f32x4 acc = {0.f, 0.f, 0.f, 0.f};
            acc = __builtin_amdgcn_mfma_f32_16x16x32_bf16(a0, b0, acc, 0, 0, 0);
            acc = __builtin_amdgcn_mfma_f32_16x16x32_bf16(a1, b1, acc, 0, 0, 0);
#pragma unroll
            for (int r = 0; r < 4; ++r) {
                int e2 = g * 4 + r;              // D row = edge
                h2w[swz128(e2, 2 * n) >> 1] = f2bf(silu_f(acc[r]));
            }
        }
        __builtin_amdgcn_wave_barrier();

        // ---- wT GEMM: B-frags from h2 (col=edge=l15), A = W3T rows ----
        bf16x8 c0 = *(const bf16x8*)&h2w[swz128(l15, g * 16) >> 1];
        bf16x8 c1 = *(const bf16x8*)&h2w[swz128(l15, 64 + g * 16) >> 1];
#pragma unroll
        for (int m0 = 0; m0 < 16; ++m0) {
            const int nrow = m0 * 16 + l15;
            bf16x8 wa0 = *(const bf16x8*)&W3T[swz128(nrow, g * 16) >> 1];
            bf16x8 wa1 = *(const bf16x8*)&W3T[swz128(nrow, 64 + g * 16) >> 1];
            f32x4 acc = {0.f, 0.f, 0.f, 0.f};
            acc = __builtin_amdgcn_mfma_f32_16x16x32_bf16(wa0, c0, acc, 0, 0, 0);
            acc = __builtin_amdgcn_mfma_f32_16x16x32_bf16(wa1, c1, acc, 0, 0, 0);
#pragma unroll
            for (int r = 0; r < 4; ++r) {
                int nn = m0 * 16 + g * 4 + r;    // D row = n
                wTw[nn * 20 + l15] = f2bf(acc[r]);   // col = edge (l15)
            }
        }
        __builtin_amdgcn_wave_barrier();

        // ---- messages: lane = channel c, 4 edges per group ----
        const int c = lane;
#pragma unroll
        for (int grp = 0; grp < 4; ++grp) {
            ushort4 qa[4];
#pragma unroll
            for (int k = 0; k < 4; ++k)
                qa[k] = *(const ushort4*)&wTw[(k * 64 + c) * 20 + grp * 4];
            const unsigned short* qp = (const unsigned short*)qa;
#pragma unroll
            for (int e = 0; e < 4; ++e) {
                const int eid = et + grp * 4 + e;
                const int sid = snd[eid];
                const int p = pos[eid];
                const float ex = ev[(size_t)eid * 3 + 0];
                const float ey = ev[(size_t)eid * 3 + 1];
                const float ez = ev[(size_t)eid * 3 + 2];
                const float ri = rsqrtf(ex * ex + ey * ey + ez * ez + 1e-12f);
                const float y0 = 1.7320508075688772f * ex * ri;
                const float y1 = 1.7320508075688772f * ey * ri;
                const float y2 = 1.7320508075688772f * ez * ri;
                const float4 xv = *(const float4*)&nf[(((size_t)sid << 6) | c) << 2];
                const float w0 = bf2f(qp[0 * 4 + e]);
                const float w1 = bf2f(qp[1 * 4 + e]);
                const float w2v = bf2f(qp[2 * 4 + e]);
                const float w3v = bf2f(qp[3 * 4 + e]);
                const float dot1 = xv.y * y0 + xv.z * y1 + xv.w * y2;
                const float m0v = w0 * xv.x + w1 * dot1;
                const float t2 = w2v * xv.x;
                ushort4 q;
                q.x = f2bf(m0v);
                q.y = f2bf(t2 * y0 + w3v * xv.y);
                q.z = f2bf(t2 * y1 + w3v * xv.z);
                q.w = f2bf(t2 * y2 + w3v * xv.w);
                *(ushort4*)&mq[((size_t)p << 8) + (c << 2)] = q;
            }
        }
        __builtin_amdgcn_wave_barrier();
    }
}

// ---------------------------------------------------------------------------
// Fused gather + node kernel: wave per node, lane = channel.
// m rows are receiver-sorted -> contiguous streaming reads.
// ---------------------------------------------------------------------------
__global__ __launch_bounds__(512, 2)
void gnode_kernel(const float* __restrict__ nf,
                  const int* __restrict__ spc,
                  const float* __restrict__ Wl0,
                  const float* __restrict__ Wl1,
                  const float* __restrict__ Ws0,
                  const float* __restrict__ Ws1,
                  const float* __restrict__ Wp0,
                  const float* __restrict__ Wp1,
                  const float* __restrict__ Wr0,
                  const float* __restrict__ Wr1,
                  const float* __restrict__ Wrd,
                  const unsigned short* __restrict__ m,
                  const int* __restrict__ off,
                  float* __restrict__ out0,
                  float* __restrict__ outF)
{
    __shared__ float L0s[4096], L1s[4096], P0s[4096], P1s[4096];  // 64 KB
    __shared__ float bufA[8][64][4];   // 8 KB
    __shared__ float bufX[8][64][4];   // 8 KB

    const int tid = threadIdx.x;
    for (int i = tid; i < 4096; i += 512) {
        L0s[i] = Wl0[i]; L1s[i] = Wl1[i]; P0s[i] = Wp0[i]; P1s[i] = Wp1[i];
    }
    __syncthreads();

    const int lane = tid & 63;
    const int wvi = tid >> 6;
    const int n = (int)(blockIdx.x << 3) | wvi;

    // ---- contiguous gather over this node's sorted message rows ----
    const int beg = off[n], end = off[n + 1];
    float4 av = make_float4(0.f, 0.f, 0.f, 0.f);
    for (int i = beg; i < end; ++i) {
        const ushort4 q = *(const ushort4*)&m[((size_t)i << 8) + (lane << 2)];
        av.x += bf2f(q.x); av.y += bf2f(q.y); av.z += bf2f(q.z); av.w += bf2f(q.w);
    }
    av.x *= 0.125f; av.y *= 0.125f; av.z *= 0.125f; av.w *= 0.125f;   // /AVG

    *(float4*)&bufA[wvi][lane][0] = av;
    const float4 xv = *(const float4*)&nf[(((size_t)n << 6) | lane) << 2];
    *(float4*)&bufX[wvi][lane][0] = xv;
    __builtin_amdgcn_wave_barrier();

    float A0 = 0.f, A1x = 0.f, A1y = 0.f, A1z = 0.f;
#pragma unroll 16
    for (int cc = 0; cc < 64; ++cc) {
        const float4 ac = *(const float4*)&bufA[wvi][cc][0];
        const float l0 = L0s[(cc << 6) | lane];
        const float l1 = L1s[(cc << 6) | lane];
        A0 += ac.x * l0; A1x += ac.y * l1; A1y += ac.z * l1; A1z += ac.w * l1;
    }

    const int s = spc[n];
    const float n1 = A1x * A1x + A1y * A1y + A1z * A1z;
    const float* w0p = &Ws0[((s << 6) | lane) * 5];
    const float A0sq = A0 * A0;
    const float B0 = w0p[0] * A0 + w0p[1] * A0sq + w0p[2] * A0sq * A0
                   + w0p[3] * n1 + w0p[4] * A0 * n1;
    const float4 w1v = *(const float4*)&Ws1[(((size_t)s << 6) | lane) << 2];
    const float gg = w1v.x + w1v.y * A0 + w1v.z * A0sq + w1v.w * n1;

    __builtin_amdgcn_wave_barrier();
    *(float4*)&bufA[wvi][lane][0] = make_float4(B0, gg * A1x, gg * A1y, gg * A1z);
    __builtin_amdgcn_wave_barrier();

    const float* wr0 = &Wr0[(size_t)s << 12];
    const float* wr1 = &Wr1[(size_t)s << 12];
    float F0 = 0.f, F1x = 0.f, F1y = 0.f, F1z = 0.f;
#pragma unroll 8
    for (int cc = 0; cc < 64; ++cc) {
        const float4 bv = *(const float4*)&bufA[wvi][cc][0];
        const float4 xc = *(const float4*)&bufX[wvi][cc][0];
        const float p0 = P0s[(cc << 6) | lane];
        const float p1 = P1s[(cc << 6) | lane];
        const float r0 = wr0[(cc << 6) | lane];
        const float r1 = wr1[(cc << 6) | lane];
        F0  += bv.x * p0 + xc.x * r0;
        F1x += bv.y * p1 + xc.y * r1;
        F1y += bv.z * p1 + xc.z * r1;
        F1z += bv.w * p1 + xc.w * r1;
    }

    *(float4*)&outF[(((size_t)n << 6) | lane) << 2] = make_float4(F0, F1x, F1y, F1z);

    float v = F0 * Wrd[lane];
#pragma unroll
    for (int o = 32; o > 0; o >>= 1) v += __shfl_down(v, o, 64);
    if (lane == 0) out0[n] = v;
}

// ===========================================================================
extern "C" void kernel_launch(void* const* d_in, const int* in_sizes, int n_in,
                              void* d_out, int out_size, void* d_ws, size_t ws_size,
                              hipStream_t stream)
{
    const float* edge_vectors = (const float*)d_in[0];
    const float* node_feats   = (const float*)d_in[1];
    const int*   node_species = (const int*)d_in[2];
    const float* radial       = (const float*)d_in[3];
    const int*   senders      = (const int*)d_in[4];
    const int*   receivers    = (const int*)d_in[5];
    const float* W_r1   = (const float*)d_in[6];
    const float* W_r2   = (const float*)d_in[7];
    const float* W_r3   = (const float*)d_in[8];
    const float* W_lin0 = (const float*)d_in[9];
    const float* W_lin1 = (const float*)d_in[10];
    const float* Wsc0   = (const float*)d_in[11];
    const float* Wsc1   = (const float*)d_in[12];
    const float* Wp0    = (const float*)d_in[13];
    const float* Wp1    = (const float*)d_in[14];
    const float* Wres0  = (const float*)d_in[15];
    const float* Wres1  = (const float*)d_in[16];
    const float* W_read = (const float*)d_in[17];

    float* out0 = (float*)d_out;
    float* outF = out0 + kN;

    char* ws = (char*)d_ws;
    unsigned short* m = (unsigned short*)(ws + kOffM);
    int* cnt = (int*)(ws + kOffCnt);
    int* off = (int*)(ws + kOffOff);
    int* cur = (int*)(ws + kOffCur);
    int* pos = (int*)(ws + kOffPos);

    hipMemsetAsync(cnt, 0, kN * sizeof(int), stream);
    hist_kernel<<<1024, 256, 0, stream>>>(receivers, cnt);
    scan_kernel<<<1, 1024, 0, stream>>>(cnt, off, cur);
    rank_kernel<<<1024, 256, 0, stream>>>(receivers, cur, pos);

    edge_mfma<<<256, 512, 0, stream>>>(edge_vectors, node_feats, radial,
                                       senders, pos, W_r1, W_r2, W_r3, m);

    gnode_kernel<<<kN / 8, 512, 0, stream>>>(node_feats, node_species,
                                             W_lin0, W_lin1, Wsc0, Wsc1,
                                             Wp0, Wp1, Wres0, Wres1, W_read,
                                             m, off, out0, outF);
}